// Round 5
// baseline (408.981 us; speedup 1.0000x reference)
//
#include <hip/hip_runtime.h>

// GNB dispersion — Round 12: per-XCD L2-local atomics.
// R8 post-mortem: agent-scope fp32 atomics bypass the (non-coherent) per-XCD L2s
// and serialize at the memory-side coherence point (189MB EA writes = 6M x 32B,
// ~20 atomics/ns -> 301us). R7/R9/R11 binning pipelines are pinned ~150us by
// record materialization + double LDS-atomic passes.
// Fix: 8 output replicas, one per XCD (HW_REG_XCC_ID). cpol=0
// global_atomic_add_f32 executes IN the local XCD L2 (atomic across that XCD's
// CUs; replica exclusivity makes cross-XCD coherence irrelevant). 400KB replica
// stays L2-resident -> atomic at L2 speed, no EA traffic until kernel-end
// writeback (the same flush every cross-kernel dataflow relies on).
//   init (zero cnrep+erep, isCN mask) -> degree (L2-local int atomics)
//   -> params (sum cn replicas) -> energy (stream edges, eval, L2-local fp32
//   atomic) -> reduce (sum 8 replicas).
// ws (words): [cnrep 8n][erep 8n][P2 2n][isCN nw]

#define EB   256
#define NXCD 8

__device__ __constant__ float2 GNB_RC6[87] = {
    {0.f, 0.f},
    {3.6516f, 95.99f},   {2.1843f, 40.67f},   {1.2711f, 70.21f},
    {3.3497f, 114.51f},  {2.7079f, 152.36f},  {1.8219f, 184.28f},
    {2.4667f, 482.54f},  {2.365f, 405.57f},   {1.5062f, 218.45f},
    {1.8233f, 174.81f},  {1.3974f, 181.7f},   {3.3515f, 263.02f},
    {3.0102f, 228.1f},   {3.1629f, 359.43f},  {3.2554f, 3222.12f},
    {2.9539f, 2144.49f}, {3.0368f, 2072.46f}, {2.6598f, 1357.42f},
    {4.0877f, 1406.65f}, {4.1275f, 1058.36f}, {9.7282f, 11498.73f},
    {8.5322f, 3361.33f}, {7.2344f, 2095.91f}, {5.3605f, 1049.31f},
    {3.718f, 966.27f},   {3.6408f, 1571.36f}, {3.4961f, 1183.59f},
    {3.5108f, 787.76f},  {3.0537f, 563.93f},  {3.0261f, 592.91f},
    {3.1735f, 430.82f},  {3.1773f, 812.57f},  {3.8357f, 4533.53f},
    {3.1109f, 3440.92f}, {3.2122f, 3859.82f}, {2.8263f, 2729.6f},
    {2.412f, 1864.19f},  {1.894f, 1175.73f},  {11.2061f, 32141.18f},
    {6.821f, 27655.14f}, {7.2367f, 2864.2f},  {3.901f, 3563.45f},
    {4.0857f, 3266.43f}, {4.045f, 3967.23f},  {3.4813f, 2233.82f},
    {3.0487f, 1393.49f}, {2.7795f, 1315.09f}, {2.8673f, 1311.47f},
    {3.3339f, 1460.56f}, {3.0086f, 1662.99f}, {3.9919f, 8089.97f},
    {3.4209f, 6887.05f}, {3.5649f, 8799.32f}, {3.0288f, 6136.5f},
    {2.262f, 3757.31f},  {1.3837f, 2561.18f}, {12.171f, 66580.83f},
    {0.f,0.f},{0.f,0.f},{0.f,0.f},{0.f,0.f},{0.f,0.f},{0.f,0.f},{0.f,0.f},
    {0.f,0.f},{0.f,0.f},{0.f,0.f},{0.f,0.f},{0.f,0.f},{0.f,0.f},{0.f,0.f},
    {6.0791f, 27593.76f}, {5.7661f, 15364.65f}, {3.6366f, 2734.5f},
    {4.241f, 4801.82f},   {4.1348f, 5685.94f},  {3.4213f, 2786.0f},
    {3.2486f, 2699.79f},  {2.9588f, 2282.6f},   {2.9381f, 2476.79f},
    {2.7711f, 2988.7f},   {2.5816f, 2506.63f},  {3.785f, 8916.84f},
    {3.5381f, 8694.22f},  {3.6985f, 11821.61f}, {3.0551f, 8410.64f},
};

// XCD id of the CU this wave runs on (0..7 on MI355X; HW-verified readable).
__device__ __forceinline__ unsigned xcd_id() {
    unsigned x;
    asm("s_getreg_b32 %0, hwreg(HW_REG_XCC_ID)" : "=s"(x));
    return x & (NXCD - 1);
}

// cpol=0 atomics: execute in the LOCAL XCD L2 (no sc bits -> not routed to the
// device coherence point). Correct here because each XCD owns its replica.
__device__ __forceinline__ void l2_atomic_fadd(float* p, float v) {
    asm volatile("global_atomic_add_f32 %0, %1, off" :: "v"(p), "v"(v));
}
__device__ __forceinline__ void l2_atomic_iadd(int* p, int v) {
    asm volatile("global_atomic_add %0, %1, off" :: "v"(p), "v"(v));
}

// Zero [cnrep 8n | erep 8n] (contiguous at ws start) + build isCN bitmask.
__global__ void gnb_init(const int* __restrict__ Z, unsigned* __restrict__ isCN,
                         int nw, int n_nodes, int4* __restrict__ zp4, long zq) {
    long stride = gridDim.x * blockDim.x;
    long t0 = blockIdx.x * blockDim.x + threadIdx.x;
    int4 z4 = make_int4(0, 0, 0, 0);
    for (long i = t0; i < zq; i += stride) zp4[i] = z4;
    for (int w = (int)t0; w < nw; w += (int)stride) {
        unsigned m = 0;
        int base = w << 5;
        int lim = n_nodes - base; if (lim > 32) lim = 32;
        for (int k = 0; k < lim; ++k) {
            int z = Z[base + k];
            if (z == 6 || z == 7) m |= (1u << k);
        }
        isCN[w] = m;
    }
}

// Degree over ALL edges; only C/N receivers (~2.3%) generate (L2-local) atomics.
__global__ void __launch_bounds__(EB)
gnb_degree(const int* __restrict__ recv, const unsigned* __restrict__ isCN,
           int* __restrict__ cnrep, int n_edges, int n_nodes) {
    int* myrep = cnrep + (size_t)xcd_id() * n_nodes;
    int base = (blockIdx.x * EB + threadIdx.x) * 4;
    if (base + 3 < n_edges) {
        int4 rv = *(const int4*)(recv + base);
        int rr[4] = {rv.x, rv.y, rv.z, rv.w};
        #pragma unroll
        for (int j = 0; j < 4; ++j) {
            unsigned r = (unsigned)rr[j];
            if ((isCN[r >> 5] >> (r & 31)) & 1u) l2_atomic_iadd(&myrep[r], 1);
        }
    } else {
        for (int j = 0; j < 4; ++j) {
            int e = base + j;
            if (e < n_edges) {
                unsigned r = (unsigned)recv[e];
                if ((isCN[r >> 5] >> (r & 31)) & 1u) l2_atomic_iadd(&myrep[r], 1);
            }
        }
    }
    asm volatile("s_waitcnt vmcnt(0)");
}

// Sum the 8 cn replicas, then derive per-node params.
__global__ void gnb_params(const int* __restrict__ Z, const int* __restrict__ cnrep,
                           float2* __restrict__ P2, int n_nodes) {
    int i = blockIdx.x * blockDim.x + threadIdx.x;
    if (i >= n_nodes) return;
    int z = Z[i];
    float Rp, C6;
    if (z == 6 || z == 7) {
        int cn = 0;
        #pragma unroll
        for (int k = 0; k < NXCD; ++k) cn += cnrep[(size_t)k * n_nodes + i];
        if (z == 6) {
            if (cn <= 3) { Rp = 2.2348f; C6 = 429.69f; }
            else         { Rp = 1.8219f; C6 = 184.28f; }
        } else {
            if (cn <= 2) { Rp = 2.6454f; C6 = 720.18f; }
            else         { Rp = 2.4667f; C6 = 482.54f; }
        }
    } else {
        float2 rc = GNB_RC6[z];
        Rp = rc.x; C6 = rc.y;
    }
    P2[i] = make_float2(sqrtf(C6), sqrtf(sqrtf(Rp)));
}

__device__ __forceinline__ float gnb_energy_eval(float2 ps, float2 pr, float rlen) {
    float env;
    if (rlen < 8.0f) {
        env = 1.0f;
    } else {
        float x = (rlen - 8.0f) * 0.5f;          // callers guarantee rlen < 10 -> x < 1
        float x2 = x * x;
        float x6 = x2 * x2 * x2;
        env = 1.0f - 28.0f * x6 + 48.0f * x6 * x - 21.0f * x6 * x2;
    }
    float sR  = ps.y * pr.y;                     // sqrt(R_ij)
    float C6  = ps.x * pr.x;                     // sqrt(C6_s*C6_r)
    float Rij = sR * sR;
    float R3  = Rij * Rij * Rij;
    float R6  = R3 * R3;
    float r0  = 0.4f * sR + 4.0f;
    float t   = r0 / rlen;
    float t2 = t * t, t4 = t2 * t2, t8 = t4 * t4;
    float t14 = t8 * t4 * t2;
    float fd = 1.0f / (1.0f + 6.0f * t14);
    float rl2 = rlen * rlen;
    float r6 = rl2 * rl2 * rl2;
    return -0.5f * C6 / (R6 + r6) * fd * env;
}

// Streaming edge kernel: vector loads, two L2-resident P2 gathers, one L2-local
// fp32 atomic per kept edge into this XCD's private replica.
__global__ void __launch_bounds__(EB)
gnb_energy(const int* __restrict__ send, const int* __restrict__ recv,
           const float* __restrict__ len, const float2* __restrict__ P2,
           float* __restrict__ erep, int n_edges, int n_nodes) {
    float* myrep = erep + (size_t)xcd_id() * n_nodes;
    int base = (blockIdx.x * EB + threadIdx.x) * 4;
    if (base + 3 < n_edges) {
        int4   sv = *(const int4*)(send + base);
        int4   rv = *(const int4*)(recv + base);
        float4 lv = *(const float4*)(len + base);
        int ss[4] = {sv.x, sv.y, sv.z, sv.w};
        int rr[4] = {rv.x, rv.y, rv.z, rv.w};
        float ll[4] = {lv.x, lv.y, lv.z, lv.w};
        #pragma unroll
        for (int j = 0; j < 4; ++j) {
            if (ll[j] < 10.0f) {
                float e = gnb_energy_eval(P2[ss[j]], P2[rr[j]], ll[j]);
                l2_atomic_fadd(&myrep[rr[j]], e);
            }
        }
    } else {
        for (int j = 0; j < 4; ++j) {
            int e = base + j;
            if (e < n_edges) {
                float l = len[e];
                if (l < 10.0f) {
                    float en = gnb_energy_eval(P2[send[e]], P2[recv[e]], l);
                    l2_atomic_fadd(&myrep[recv[e]], en);
                }
            }
        }
    }
    asm volatile("s_waitcnt vmcnt(0)");
}

// Sum the 8 energy replicas (coherent after energy's kernel-end L2 writeback).
__global__ void gnb_reduce(const float* __restrict__ erep, float* __restrict__ out,
                           int n_nodes) {
    int i = blockIdx.x * blockDim.x + threadIdx.x;
    if (i >= n_nodes) return;
    float s = 0.0f;
    #pragma unroll
    for (int k = 0; k < NXCD; ++k) s += erep[(size_t)k * n_nodes + i];
    out[i] = s;
}

extern "C" void kernel_launch(void* const* d_in, const int* in_sizes, int n_in,
                              void* d_out, int out_size, void* d_ws, size_t ws_size,
                              hipStream_t stream) {
    const int*   Z    = (const int*)d_in[0];
    const int*   eidx = (const int*)d_in[1];
    const float* len  = (const float*)d_in[2];
    float*       out  = (float*)d_out;

    const int n_nodes = in_sizes[0];
    const int n_edges = in_sizes[2];
    const int* send = eidx;
    const int* recv = eidx + n_edges;

    const int nw = (n_nodes + 31) >> 5;

    // ws layout (words): [cnrep 8n][erep 8n][P2 2n][isCN nw]
    char* ws = (char*)d_ws;
    int*      cnrep = (int*)ws;
    float*    erep  = (float*)(ws + (size_t)NXCD * n_nodes * 4);
    float2*   P2    = (float2*)(ws + (size_t)2 * NXCD * n_nodes * 4);
    unsigned* isCN  = (unsigned*)(ws + ((size_t)2 * NXCD + 2) * n_nodes * 4);

    long zwords = (long)2 * NXCD * n_nodes;      // cnrep + erep, contiguous
    long zq     = zwords / 4;                    // divisible (16n)

    const int B = 256;
    int node_blocks = (n_nodes + B - 1) / B;
    int edge_blocks = (n_edges + EB * 4 - 1) / (EB * 4);

    gnb_init<<<256, B, 0, stream>>>(Z, isCN, nw, n_nodes, (int4*)ws, zq);
    gnb_degree<<<edge_blocks, EB, 0, stream>>>(recv, isCN, cnrep, n_edges, n_nodes);
    gnb_params<<<node_blocks, B, 0, stream>>>(Z, cnrep, P2, n_nodes);
    gnb_energy<<<edge_blocks, EB, 0, stream>>>(send, recv, len, P2, erep,
                                               n_edges, n_nodes);
    gnb_reduce<<<node_blocks, B, 0, stream>>>(erep, out, n_nodes);
}

// Round 7
// 232.216 us; speedup vs baseline: 1.7612x; 1.7612x over previous
//
#include <hip/hip_runtime.h>

// GNB dispersion — Round 14: resubmit of R13 (container infra failure x2, no
// counters — same signature as R2, which passed on identical resubmit in R3).
// R12 refuted L2-local atomics (WRITE_SIZE 189MB identical to R8 -> fp32 atomics
// always serialize at the memory-side point, ~20/ns). Binned pipeline stays.
// vs R9/R11: single block hist[128] whose atomic-return IS the final in-block
// offset (no per-wave hist, no scan, 2 barriers, ~1KB LDS), and records packed
// to 4B: e rounded to 13 mantissa bits, rlow in low 10 bits. Accum is gather-
// free, uint4-vectorized, 4 LDS replicas, and absorbs the overflow list.
//   init -> degree -> params -> scatter(+eval) -> accum -> reduce
// ws (words): [cursor 128][ocur 8][cn n][P2 2n][isCN nwp]
//             [rep NB2*ES*1024][ovrec uint2 ocap][buckets uint NB2*cap]

#define B2SHIFT 10
#define B2SIZE  1024
#define TILE    4096
#define SBLK    512
#define ESLICES 32
#define MAXB    128
#define EB      256
#define AREP    4

__device__ __constant__ float2 GNB_RC6[87] = {
    {0.f, 0.f},
    {3.6516f, 95.99f},   {2.1843f, 40.67f},   {1.2711f, 70.21f},
    {3.3497f, 114.51f},  {2.7079f, 152.36f},  {1.8219f, 184.28f},
    {2.4667f, 482.54f},  {2.365f, 405.57f},   {1.5062f, 218.45f},
    {1.8233f, 174.81f},  {1.3974f, 181.7f},   {3.3515f, 263.02f},
    {3.0102f, 228.1f},   {3.1629f, 359.43f},  {3.2554f, 3222.12f},
    {2.9539f, 2144.49f}, {3.0368f, 2072.46f}, {2.6598f, 1357.42f},
    {4.0877f, 1406.65f}, {4.1275f, 1058.36f}, {9.7282f, 11498.73f},
    {8.5322f, 3361.33f}, {7.2344f, 2095.91f}, {5.3605f, 1049.31f},
    {3.718f, 966.27f},   {3.6408f, 1571.36f}, {3.4961f, 1183.59f},
    {3.5108f, 787.76f},  {3.0537f, 563.93f},  {3.0261f, 592.91f},
    {3.1735f, 430.82f},  {3.1773f, 812.57f},  {3.8357f, 4533.53f},
    {3.1109f, 3440.92f}, {3.2122f, 3859.82f}, {2.8263f, 2729.6f},
    {2.412f, 1864.19f},  {1.894f, 1175.73f},  {11.2061f, 32141.18f},
    {6.821f, 27655.14f}, {7.2367f, 2864.2f},  {3.901f, 3563.45f},
    {4.0857f, 3266.43f}, {4.045f, 3967.23f},  {3.4813f, 2233.82f},
    {3.0487f, 1393.49f}, {2.7795f, 1315.09f}, {2.8673f, 1311.47f},
    {3.3339f, 1460.56f}, {3.0086f, 1662.99f}, {3.9919f, 8089.97f},
    {3.4209f, 6887.05f}, {3.5649f, 8799.32f}, {3.0288f, 6136.5f},
    {2.262f, 3757.31f},  {1.3837f, 2561.18f}, {12.171f, 66580.83f},
    {0.f,0.f},{0.f,0.f},{0.f,0.f},{0.f,0.f},{0.f,0.f},{0.f,0.f},{0.f,0.f},
    {0.f,0.f},{0.f,0.f},{0.f,0.f},{0.f,0.f},{0.f,0.f},{0.f,0.f},{0.f,0.f},
    {6.0791f, 27593.76f}, {5.7661f, 15364.65f}, {3.6366f, 2734.5f},
    {4.241f, 4801.82f},   {4.1348f, 5685.94f},  {3.4213f, 2786.0f},
    {3.2486f, 2699.79f},  {2.9588f, 2282.6f},   {2.9381f, 2476.79f},
    {2.7711f, 2988.7f},   {2.5816f, 2506.63f},  {3.785f, 8916.84f},
    {3.5381f, 8694.22f},  {3.6985f, 11821.61f}, {3.0551f, 8410.64f},
};

// Zero [cursor|ocur|cn] (contiguous at ws start) + build isCN bitmask.
__global__ void gnb_init(const int* __restrict__ Z, unsigned* __restrict__ isCN,
                         int nw, int n_nodes, int4* __restrict__ zp4, int zq,
                         int* __restrict__ zp, int zwords) {
    int stride = gridDim.x * blockDim.x;
    int t0 = blockIdx.x * blockDim.x + threadIdx.x;
    int4 z4 = make_int4(0, 0, 0, 0);
    for (int i = t0; i < zq; i += stride) zp4[i] = z4;
    for (int i = zq * 4 + t0; i < zwords; i += stride) zp[i] = 0;
    for (int w = t0; w < nw; w += stride) {
        unsigned m = 0;
        int base = w << 5;
        int lim = n_nodes - base; if (lim > 32) lim = 32;
        for (int k = 0; k < lim; ++k) {
            int z = Z[base + k];
            if (z == 6 || z == 7) m |= (1u << k);
        }
        isCN[w] = m;
    }
}

// Degree over ALL edges; only C/N receivers (~2.3% -> ~150K atomics) hit global.
__global__ void __launch_bounds__(EB)
gnb_degree(const int* __restrict__ recv, const unsigned* __restrict__ isCN,
           int* __restrict__ cn, int n_edges) {
    int base = (blockIdx.x * EB + threadIdx.x) * 4;
    if (base + 3 < n_edges) {
        int4 rv = *(const int4*)(recv + base);
        int rr[4] = {rv.x, rv.y, rv.z, rv.w};
        #pragma unroll
        for (int j = 0; j < 4; ++j) {
            unsigned r = (unsigned)rr[j];
            if ((isCN[r >> 5] >> (r & 31)) & 1u) atomicAdd(&cn[r], 1);
        }
    } else {
        for (int j = 0; j < 4; ++j) {
            int e = base + j;
            if (e < n_edges) {
                unsigned r = (unsigned)recv[e];
                if ((isCN[r >> 5] >> (r & 31)) & 1u) atomicAdd(&cn[r], 1);
            }
        }
    }
}

__global__ void gnb_params(const int* __restrict__ Z, const int* __restrict__ cn,
                           float2* __restrict__ P2, int n_nodes) {
    int i = blockIdx.x * blockDim.x + threadIdx.x;
    if (i >= n_nodes) return;
    int z = Z[i];
    float Rp, C6;
    if (z == 6) {
        if (cn[i] <= 3) { Rp = 2.2348f; C6 = 429.69f; }
        else            { Rp = 1.8219f; C6 = 184.28f; }
    } else if (z == 7) {
        if (cn[i] <= 2) { Rp = 2.6454f; C6 = 720.18f; }
        else            { Rp = 2.4667f; C6 = 482.54f; }
    } else {
        float2 rc = GNB_RC6[z];
        Rp = rc.x; C6 = rc.y;
    }
    P2[i] = make_float2(sqrtf(C6), sqrtf(sqrtf(Rp)));
}

__device__ __forceinline__ float gnb_energy_eval(float2 ps, float2 pr, float rlen) {
    float env;
    if (rlen < 8.0f) {
        env = 1.0f;
    } else {
        float x = (rlen - 8.0f) * 0.5f;          // callers guarantee rlen < 10 -> x < 1
        float x2 = x * x;
        float x6 = x2 * x2 * x2;
        env = 1.0f - 28.0f * x6 + 48.0f * x6 * x - 21.0f * x6 * x2;
    }
    float sR  = ps.y * pr.y;                     // sqrt(R_ij)
    float C6  = ps.x * pr.x;                     // sqrt(C6_s*C6_r)
    float Rij = sR * sR;
    float R3  = Rij * Rij * Rij;
    float R6  = R3 * R3;
    float r0  = 0.4f * sR + 4.0f;
    float t   = r0 / rlen;
    float t2 = t * t, t4 = t2 * t2, t8 = t4 * t4;
    float t14 = t8 * t4 * t2;
    float fd = 1.0f / (1.0f + 6.0f * t14);
    float rl2 = rlen * rlen;
    float r6 = rl2 * rl2 * rl2;
    return -0.5f * C6 / (R6 + r6) * fd * env;
}

// Lean scatter: eval + one LDS atomic (return = final in-block offset) ->
// barrier -> reserve -> barrier -> direct 4B store from registers.
// Record: ebits rounded to 13 mantissa bits | rlow (low 10 bits).
__global__ void __launch_bounds__(SBLK)
gnb_scatter(const int* __restrict__ send, const int* __restrict__ recv,
            const float* __restrict__ len, const float2* __restrict__ P2,
            unsigned* __restrict__ buckets, unsigned* __restrict__ cursor,
            uint2* __restrict__ ovrec, unsigned* __restrict__ ocur,
            int n_edges, unsigned cap, unsigned ocap) {
    __shared__ unsigned hist[MAXB];
    __shared__ unsigned gbase[MAXB];
    const int tid = threadIdx.x;
    const int e0  = blockIdx.x * TILE;

    if (tid < MAXB) hist[tid] = 0;
    __syncthreads();

    unsigned pk[2][4];   // record bits (ebits_rounded | rlow)
    unsigned bk[2][4];   // b | off<<7 ; 0xFFFFFFFF = not kept
    const bool full = (e0 + TILE <= n_edges);
    #pragma unroll
    for (int k = 0; k < 2; ++k) {
        int base = e0 + (k * SBLK + tid) * 4;
        int ss[4]; int rr[4]; float ll[4];
        if (full) {
            int4   sv = *(const int4*)(send + base);
            int4   rv = *(const int4*)(recv + base);
            float4 lv = *(const float4*)(len + base);
            ss[0]=sv.x; ss[1]=sv.y; ss[2]=sv.z; ss[3]=sv.w;
            rr[0]=rv.x; rr[1]=rv.y; rr[2]=rv.z; rr[3]=rv.w;
            ll[0]=lv.x; ll[1]=lv.y; ll[2]=lv.z; ll[3]=lv.w;
        } else {
            for (int j = 0; j < 4; ++j) {
                int e = base + j;
                bool ok = (e < n_edges);
                ss[j] = ok ? send[e] : 0;
                rr[j] = ok ? recv[e] : 0;
                ll[j] = ok ? len[e]  : 1.0e9f;
            }
        }
        #pragma unroll
        for (int j = 0; j < 4; ++j) {
            if (ll[j] < 10.0f) {
                float e = gnb_energy_eval(P2[ss[j]], P2[rr[j]], ll[j]);
                unsigned eb = (__float_as_uint(e) + 512u) & ~1023u;  // RN to 13-bit mantissa
                unsigned r  = (unsigned)rr[j];
                unsigned b  = r >> B2SHIFT;
                unsigned off = atomicAdd(&hist[b], 1u);   // return = final in-block offset
                pk[k][j] = eb | (r & (B2SIZE - 1));
                bk[k][j] = b | (off << 7);
            } else {
                bk[k][j] = 0xFFFFFFFFu;
            }
        }
    }
    __syncthreads();

    if (tid < MAXB) {
        unsigned c = hist[tid];
        gbase[tid] = c ? atomicAdd(&cursor[tid], c) : 0u;
    }
    __syncthreads();

    #pragma unroll
    for (int k = 0; k < 2; ++k) {
        #pragma unroll
        for (int j = 0; j < 4; ++j) {
            unsigned bo = bk[k][j];
            if (bo != 0xFFFFFFFFu) {
                unsigned b = bo & (MAXB - 1);
                unsigned g = gbase[b] + (bo >> 7);
                if (g < cap) {
                    buckets[(size_t)b * cap + g] = pk[k][j];
                } else {
                    unsigned o = atomicAdd(ocur, 1u);
                    if (o < ocap)
                        ovrec[o] = make_uint2((b << B2SHIFT) | (pk[k][j] & (B2SIZE - 1)),
                                              pk[k][j] & ~1023u);
                }
            }
        }
    }
}

// Gather-free accumulate: uint4 record stream -> LDS fp32 add, 4 replicas.
// Slice-0 blocks also fold in the (normally empty) overflow list.
__global__ void __launch_bounds__(256)
gnb_accum(const unsigned* __restrict__ buckets, const unsigned* __restrict__ cursor,
          const uint2* __restrict__ ovrec, const unsigned* __restrict__ ocur,
          float* __restrict__ rep, unsigned cap, unsigned ocap) {
    __shared__ float acc[AREP][B2SIZE + 8];
    const int b   = blockIdx.x / ESLICES;
    const int sl  = blockIdx.x % ESLICES;
    const int tid = threadIdx.x;
    const int rr  = (tid >> 6) & (AREP - 1);

    for (int i = tid; i < AREP * (B2SIZE + 8); i += 256) acc[0][i] = 0.0f;
    __syncthreads();

    unsigned count = cursor[b];
    if (count > cap) count = cap;
    unsigned seg = (((count + ESLICES - 1) / ESLICES) + 3u) & ~3u;   // 4-aligned
    unsigned st  = (unsigned)sl * seg; if (st > count) st = count;
    unsigned en  = st + seg; if (en > count) en = count;

    const unsigned* src = buckets + (size_t)b * cap;
    for (unsigned i = st + tid * 4; i < en; i += 1024) {
        if (i + 4 <= en) {
            uint4 v = *(const uint4*)(src + i);
            atomicAdd(&acc[rr][v.x & (B2SIZE - 1)], __uint_as_float(v.x & ~1023u));
            atomicAdd(&acc[rr][v.y & (B2SIZE - 1)], __uint_as_float(v.y & ~1023u));
            atomicAdd(&acc[rr][v.z & (B2SIZE - 1)], __uint_as_float(v.z & ~1023u));
            atomicAdd(&acc[rr][v.w & (B2SIZE - 1)], __uint_as_float(v.w & ~1023u));
        } else {
            for (unsigned t = i; t < en; ++t) {
                unsigned v = src[t];
                atomicAdd(&acc[rr][v & (B2SIZE - 1)], __uint_as_float(v & ~1023u));
            }
        }
    }

    if (sl == 0) {                    // overflow fold (usually n == 0)
        unsigned n = *ocur; if (n > ocap) n = ocap;
        for (unsigned i = tid; i < n; i += 256) {
            uint2 rc = ovrec[i];
            if ((rc.x >> B2SHIFT) == (unsigned)b)
                atomicAdd(&acc[rr][rc.x & (B2SIZE - 1)], __uint_as_float(rc.y));
        }
    }
    __syncthreads();

    float* dst = rep + (size_t)blockIdx.x * B2SIZE;
    for (int i = tid; i < B2SIZE; i += 256)
        dst[i] = (acc[0][i] + acc[1][i]) + (acc[2][i] + acc[3][i]);
}

__global__ void gnb_reduce(const float* __restrict__ rep, float* __restrict__ out,
                           int n_nodes) {
    int i = blockIdx.x * blockDim.x + threadIdx.x;
    if (i >= n_nodes) return;
    int b = i >> B2SHIFT;
    int j = i & (B2SIZE - 1);
    const float* src = rep + ((size_t)b * ESLICES) * B2SIZE + j;
    float sum = 0.0f;
    #pragma unroll
    for (int s = 0; s < ESLICES; ++s) sum += src[(size_t)s * B2SIZE];
    out[i] = sum;
}

extern "C" void kernel_launch(void* const* d_in, const int* in_sizes, int n_in,
                              void* d_out, int out_size, void* d_ws, size_t ws_size,
                              hipStream_t stream) {
    const int*   Z    = (const int*)d_in[0];
    const int*   eidx = (const int*)d_in[1];
    const float* len  = (const float*)d_in[2];
    float*       out  = (float*)d_out;

    const int n_nodes = in_sizes[0];
    const int n_edges = in_sizes[2];
    const int* send = eidx;
    const int* recv = eidx + n_edges;

    const int NB2 = (n_nodes + B2SIZE - 1) >> B2SHIFT;   // 98 for n=100000
    const int nw  = (n_nodes + 31) >> 5;
    const int nwp = (nw + 7) & ~7;

    // ws layout (words): [cursor 128][ocur 8][cn n][P2 2n][isCN nwp][rep][tail]
    char* ws = (char*)d_ws;
    unsigned* cursor = (unsigned*)ws;                                          // 128
    unsigned* ocur   = (unsigned*)(ws + MAXB * 4);                             // 8
    int*      cn     = (int*)(ws + (MAXB + 8) * 4);                            // n
    float2*   P2     = (float2*)(ws + ((size_t)n_nodes + MAXB + 8) * 4);       // 2n
    unsigned* isCN   = (unsigned*)(ws + ((size_t)3 * n_nodes + MAXB + 8) * 4); // nwp
    float*    rep    = (float*)((char*)isCN + (size_t)nwp * 4);
    size_t rep_w     = (size_t)NB2 * ESLICES * B2SIZE;
    char*     tail   = (char*)rep + rep_w * 4;

    size_t fixed_words = (size_t)3 * n_nodes + MAXB + 8 + nwp + rep_w;
    size_t total_words = ws_size / 4;
    size_t avail = total_words > fixed_words ? total_words - fixed_words : 0;
    size_t ovw = avail / 64;                      // ~1.5% to overflow queue
    unsigned ocap = (unsigned)((ovw / 2) & ~1ull);        // uint2, 16B-align next
    size_t capw = (avail - ovw) / (size_t)NB2;
    capw &= ~(size_t)3;                           // 16B-aligned bucket rows
    long cap = (long)capw;
    if (cap > n_edges) cap = (n_edges + 3) & ~3;
    if (cap < 0) cap = 0;
    uint2*    ovrec   = (uint2*)tail;
    unsigned* buckets = (unsigned*)(tail + (size_t)ocap * 8);

    const int B = 256;
    int node_blocks = (n_nodes + B - 1) / B;
    int edge4_blocks = (n_edges + EB * 4 - 1) / (EB * 4);
    int scat_blocks = (n_edges + TILE - 1) / TILE;
    int zero_words  = n_nodes + MAXB + 8;         // cursor + ocur + cn
    int zq = zero_words / 4;

    gnb_init<<<256, B, 0, stream>>>(Z, isCN, nw, n_nodes, (int4*)ws, zq,
                                    (int*)ws, zero_words);
    gnb_degree<<<edge4_blocks, EB, 0, stream>>>(recv, isCN, cn, n_edges);
    gnb_params<<<node_blocks, B, 0, stream>>>(Z, cn, P2, n_nodes);
    gnb_scatter<<<scat_blocks, SBLK, 0, stream>>>(send, recv, len, P2, buckets,
                                                  cursor, ovrec, ocur, n_edges,
                                                  (unsigned)cap, ocap);
    gnb_accum<<<NB2 * ESLICES, B, 0, stream>>>(buckets, cursor, ovrec, ocur,
                                               rep, (unsigned)cap, ocap);
    gnb_reduce<<<node_blocks, B, 0, stream>>>(rep, out, n_nodes);
}